// Round 12
// baseline (223.198 us; speedup 1.0000x reference)
//
#include <hip/hip_runtime.h>

#define N_HALF 8192
#define D 128
#define NBLK 2080

typedef __bf16 bf16x8 __attribute__((ext_vector_type(8)));
typedef float f32x4 __attribute__((ext_vector_type(4)));

// ws layout (4327440 B):
// [0,       4194304)  bfS     -- bf16 features, MFMA-fragment-major:
//                        frag(T,kk,ni): elem ((T*4+kk)*4+ni)*512 + lane*8 + j
//                        holds row T*64+ni*16+(lane&15), k = kk*32+(lane>>4)*8+j
// [4194304, 4259840)  sq      (16384 f32)  -- exact fp32 |row|^2
// [4259840, 4292608)  U       (8192 f32)   -- rowsum_aa + rowsum_ab
// [4292608, 4325376)  V       (8192 f32)   -- colsum_ab + rowsum_bb
// [4325376, 4327424)  alignP  (512 f32)    -- per-prep-block align partials
// [4327424, 4327440)  ctr     (4 u32)      -- 0: blocks-done counter
#define OFF_SQ 4194304
#define OFF_U  4259840
#define OFF_V  4292608
#define OFF_AL 4325376
#define OFF_CT 4327424

__device__ __forceinline__ unsigned short f2bf(float f) {
    unsigned int u = __float_as_uint(f);
    u += 0x7fffu + ((u >> 16) & 1u);   // round-to-nearest-even
    return (unsigned short)(u >> 16);
}

__device__ __forceinline__ void async_cp16(const unsigned short* g, unsigned short* l) {
    __builtin_amdgcn_global_load_lds(
        (const __attribute__((address_space(1))) void*)g,
        (__attribute__((address_space(3))) void*)l, 16, 0, 0);
}

// ---- prep: block-local fragment emission (proven R9/R11 version) + ctr zero
__global__ __launch_bounds__(256) void prep_kernel(
    const float* __restrict__ feats, unsigned short* __restrict__ bfS,
    float* __restrict__ sq, float* __restrict__ U, float* __restrict__ V,
    float* __restrict__ alignP, unsigned int* __restrict__ ctr)
{
    __shared__ float ld[32 * 132];
    __shared__ float nrm[32];
    __shared__ float alg[16];

    const int b = blockIdx.x;        // 0..511
    const int t = threadIdx.x;
    const int A0 = b * 16;

#pragma unroll
    for (int it = 0; it < 4; ++it) {
        int idx = it * 256 + t;
        int row = idx >> 5;
        int c4 = idx & 31;
        int grow = (row < 16) ? (A0 + row) : (N_HALF + A0 + row - 16);
        *(float4*)&ld[row * 132 + c4 * 4] =
            *(const float4*)(feats + (size_t)grow * D + c4 * 4);
    }
    if (t < 16)       U[A0 + t] = 0.f;
    else if (t < 32)  V[A0 + t - 16] = 0.f;
    if (b == 0 && t >= 32 && t < 36) ctr[t - 32] = 0u;
    __syncthreads();

    const int wave = t >> 6, lane = t & 63;
    {   // norms
        int r = 8 * wave + (lane >> 3);
        int k0 = (lane & 7) * 16;
        float s = 0.f;
#pragma unroll
        for (int k = 0; k < 16; k += 4) {
            float4 v = *(const float4*)&ld[r * 132 + k0 + k];
            s += v.x * v.x + v.y * v.y + v.z * v.z + v.w * v.w;
        }
        s += __shfl_xor(s, 1);
        s += __shfl_xor(s, 2);
        s += __shfl_xor(s, 4);
        if ((lane & 7) == 0) {
            nrm[r] = s;
            int grow = (r < 16) ? (A0 + r) : (N_HALF + A0 + r - 16);
            sq[grow] = s;
        }
    }
    __syncthreads();
    if (wave < 2) {   // exact diag alignment term
        int r = 8 * wave + (lane >> 3);
        int k0 = (lane & 7) * 16;
        float s = 0.f;
#pragma unroll
        for (int k = 0; k < 16; k += 4) {
            float4 a = *(const float4*)&ld[r * 132 + k0 + k];
            float4 bb = *(const float4*)&ld[(r + 16) * 132 + k0 + k];
            s += a.x * bb.x + a.y * bb.y + a.z * bb.z + a.w * bb.w;
        }
        s += __shfl_xor(s, 1);
        s += __shfl_xor(s, 2);
        s += __shfl_xor(s, 4);
        if ((lane & 7) == 0) {
            float d2 = fmaxf(nrm[r] + nrm[r + 16] - 2.0f * s, 0.0f);
            alg[r] = -__logf(d2 + 1.0f);
        }
    }
    const int l = (t >> 2) & 15, j2 = t & 3, q = t >> 6;
    const int Ta = b >> 2, ni = b & 3;
#pragma unroll
    for (int kk = 0; kk < 4; ++kk) {
        float2 va = *(const float2*)&ld[l * 132 + kk * 32 + q * 8 + j2 * 2];
        float2 vb = *(const float2*)&ld[(l + 16) * 132 + kk * 32 + q * 8 + j2 * 2];
        unsigned int ua = ((unsigned int)f2bf(va.y) << 16) | f2bf(va.x);
        unsigned int ub = ((unsigned int)f2bf(vb.y) << 16) | f2bf(vb.x);
        ((unsigned int*)bfS)[((size_t)((Ta * 4 + kk) * 4 + ni)) * 256 + t] = ua;
        ((unsigned int*)bfS)[((size_t)(((128 + Ta) * 4 + kk) * 4 + ni)) * 256 + t] = ub;
    }
    __syncthreads();
    if (t == 0) {
        float s = 0.f;
#pragma unroll
        for (int r = 0; r < 16; ++r) s += alg[r];
        alignP[b] = s;
    }
}

// ---- band kernel: block = 256-row band x 4 col-tiles(64). 4 stacked waves x 64 rows.
// A in regs (af[4][4], scaled -2); B 16KB/step LDS dbuf via contiguous DMA;
// per-sim LDS/VALU overhead halved vs 32-row waves (16 ds_read per 4096 sims).
// Jobs: ab 1024 + aa 528 + bb 528 = 2080 x 4-step. Tail fused via done-counter.
__global__ __launch_bounds__(256, 3) void band_kernel(
    const unsigned short* __restrict__ bfS, const float* __restrict__ sq,
    float* __restrict__ U, float* __restrict__ V,
    const float* __restrict__ alignP, unsigned int* __restrict__ ctr,
    unsigned int* __restrict__ out)
{
    __shared__ unsigned short lB[2][8192];   // 2 x 16 KB
    __shared__ float ps[4];
    __shared__ int lastFlag;

    int kind, band, c0;
    {
        int id = blockIdx.x;
        if (id < 1024) { kind = 0; band = id & 31; c0 = id >> 5; }
        else {
            int t = id - 1024;
            kind = 1;
            if (t >= 528) { t -= 528; kind = 2; }
            int bb_ = 0;
            while (t >= 32 - bb_) { t -= 32 - bb_; ++bb_; }   // <=31 iters, scalar
            band = bb_; c0 = bb_ + t;
        }
    }
    const int js = c0 * 4, je = js + 4;
    const bool sym = (kind != 0);

    const int wave = threadIdx.x >> 6, lane = threadIdx.x & 63;
    const int l15 = lane & 15, quad = lane >> 4;

    const int rtile = band * 4 + wave;            // wave's 64-row tile (0..127)
    const int wRow0 = rtile * 64;                 // within-half row base
    const int T_A = (kind == 2 ? 128 : 0) + rtile;
    const int T_B0 = (kind == 1 ? 0 : 128);
    const int rowSqB = (kind == 2 ? N_HALF : 0);
    const int colSqB = (kind == 1 ? 0 : N_HALF);
    float* const rowDst = (kind == 2) ? V : U;
    float* const colDst = (kind == 1) ? U : V;

    // A fragments (64 rows), scaled by -2 exactly: (x^0x8000)+0x0080 per bf16
    bf16x8 af[4][4];
#pragma unroll
    for (int mi = 0; mi < 4; ++mi)
#pragma unroll
        for (int kk = 0; kk < 4; ++kk) {
            union { uint4 u; bf16x8 v; } c;
            c.u = *(const uint4*)(bfS + ((size_t)((T_A * 4 + kk) * 4 + mi)) * 512 + lane * 8);
            c.u.x = (c.u.x ^ 0x80008000u) + 0x00800080u;
            c.u.y = (c.u.y ^ 0x80008000u) + 0x00800080u;
            c.u.z = (c.u.z ^ 0x80008000u) + 0x00800080u;
            c.u.w = (c.u.w ^ 0x80008000u) + 0x00800080u;
            af[mi][kk] = c.v;
        }

    float rs1[16];
#pragma unroll
    for (int mi = 0; mi < 4; ++mi)
#pragma unroll
        for (int r = 0; r < 4; ++r)
            rs1[mi * 4 + r] = sq[rowSqB + wRow0 + mi * 16 + quad * 4 + r] + 1.0f;

    float rowAcc[16];
#pragma unroll
    for (int x = 0; x < 16; ++x) rowAcc[x] = 0.f;

    // stage tile t (16 KB contiguous): wave copies 4KB via 4 x 1KB DMA instrs
    auto stage = [&](int t, int s) {
        const unsigned short* src = bfS + ((size_t)(T_B0 + t)) * 8192 + wave * 2048 + lane * 8;
        unsigned short* dst = &lB[s][wave * 2048];
#pragma unroll
        for (int k = 0; k < 4; ++k)
            async_cp16(src + k * 512, dst + k * 512);
    };

    stage(js, 0);
    float csqN[4];
#pragma unroll
    for (int ni = 0; ni < 4; ++ni)
        csqN[ni] = sq[colSqB + js * 64 + ni * 16 + l15];

    float savedCol[4];
    int savedJ = -1;

    for (int t = js; t < je; ++t) {
        const int s = (t - js) & 1;
        __syncthreads();                 // drains DMA(t) + prev-step atomics
        if (t + 1 < je) stage(t + 1, s ^ 1);

        if (savedJ >= 0) {               // flush previous step's col atomics
#pragma unroll
            for (int ni = 0; ni < 4; ++ni) {
                float cv = savedCol[ni];
                cv += __shfl_xor(cv, 16);
                cv += __shfl_xor(cv, 32);
                if (quad == 0) atomicAdd(&colDst[savedJ + ni * 16 + l15], cv);
            }
            savedJ = -1;
        }

        const int jn = (t + 1 < je) ? t + 1 : t;
        float csq[4] = {csqN[0], csqN[1], csqN[2], csqN[3]};
#pragma unroll
        for (int ni = 0; ni < 4; ++ni)
            csqN[ni] = sq[colSqB + jn * 64 + ni * 16 + l15];

        if (sym && t < rtile) continue;  // tile fully below this wave's diagonal

        // acc init = |a|^2 + |b|^2 + 1; MFMA adds -2*dot => acc = d2+1
        f32x4 acc[4][4];
#pragma unroll
        for (int mi = 0; mi < 4; ++mi)
#pragma unroll
            for (int ni = 0; ni < 4; ++ni)
#pragma unroll
                for (int r = 0; r < 4; ++r)
                    acc[mi][ni][r] = rs1[mi * 4 + r] + csq[ni];

#pragma unroll
        for (int kk = 0; kk < 4; ++kk) {
            bf16x8 bfr[4];
#pragma unroll
            for (int ni = 0; ni < 4; ++ni)
                bfr[ni] = *(const bf16x8*)&lB[s][(kk * 4 + ni) * 512 + lane * 8];
#pragma unroll
            for (int mi = 0; mi < 4; ++mi)
#pragma unroll
                for (int ni = 0; ni < 4; ++ni)
                    acc[mi][ni] = __builtin_amdgcn_mfma_f32_16x16x32_bf16(
                        af[mi][kk], bfr[ni], acc[mi][ni], 0, 0, 0);
        }

        const bool maskDiag = sym && (t == rtile);
        float colPart[4] = {0.f, 0.f, 0.f, 0.f};
#pragma unroll
        for (int mi = 0; mi < 4; ++mi)
#pragma unroll
            for (int ni = 0; ni < 4; ++ni)
#pragma unroll
                for (int r = 0; r < 4; ++r) {
                    float sim = __builtin_amdgcn_rcpf(fmaxf(acc[mi][ni][r], 1.0f));
                    if (maskDiag && (ni * 16 + l15) <= (mi * 16 + quad * 4 + r))
                        sim = 0.0f;      // strict upper only on diagonal tiles
                    rowAcc[mi * 4 + r] += sim;
                    colPart[ni] += sim;
                }
#pragma unroll
        for (int ni = 0; ni < 4; ++ni) savedCol[ni] = colPart[ni];
        savedJ = t * 64;
    }

    if (savedJ >= 0) {   // final col flush
#pragma unroll
        for (int ni = 0; ni < 4; ++ni) {
            float cv = savedCol[ni];
            cv += __shfl_xor(cv, 16);
            cv += __shfl_xor(cv, 32);
            if (quad == 0) atomicAdd(&colDst[savedJ + ni * 16 + l15], cv);
        }
    }
    // row flush: reduce over 16 l15 lanes, one atomic per row, once per job
#pragma unroll
    for (int x = 0; x < 16; ++x) {
        float v = rowAcc[x];
        v += __shfl_xor(v, 1);
        v += __shfl_xor(v, 2);
        v += __shfl_xor(v, 4);
        v += __shfl_xor(v, 8);
        if (l15 == 0)
            atomicAdd(&rowDst[wRow0 + (x >> 2) * 16 + quad * 4 + (x & 3)], v);
    }

    // ---- fused tail: last block reduces U/V + alignP (R10-proven mechanics)
    __syncthreads();
    if (threadIdx.x == 0) {
        __threadfence();
        unsigned int old = atomicAdd(&ctr[0], 1u);
        lastFlag = (old == (unsigned int)(NBLK - 1));
    }
    __syncthreads();
    if (lastFlag) {
        float sum = 0.f;
        for (int i = threadIdx.x; i < N_HALF; i += 256) {
            float u = __hip_atomic_load(&U[i], __ATOMIC_RELAXED, __HIP_MEMORY_SCOPE_AGENT);
            float v = __hip_atomic_load(&V[i], __ATOMIC_RELAXED, __HIP_MEMORY_SCOPE_AGENT);
            sum += __logf(u) + __logf(v);
        }
        float a = 0.f;
        for (int i = threadIdx.x; i < 512; i += 256) a += alignP[i];
        float m = a - 0.5f * sum;
#pragma unroll
        for (int off = 32; off; off >>= 1) m += __shfl_xor(m, off);
        if (lane == 0) ps[wave] = m;
        __syncthreads();
        if (threadIdx.x == 0) {
            float loss = -((ps[0] + ps[1] + ps[2] + ps[3]) / (float)N_HALF);
            unsigned int h = (unsigned int)f2bf(loss);
            out[0] = (h << 16) | h;   // fp32 reader: loss @ bf16 precision
        }
    }
}

extern "C" void kernel_launch(void* const* d_in, const int* in_sizes, int n_in,
                              void* d_out, int out_size, void* d_ws, size_t ws_size,
                              hipStream_t stream)
{
    const float* feats = (const float*)d_in[0];
    unsigned int* out = (unsigned int*)d_out;
    char* ws = (char*)d_ws;
    unsigned short* bfS = (unsigned short*)(ws);
    float* sq     = (float*)(ws + OFF_SQ);
    float* U      = (float*)(ws + OFF_U);
    float* V      = (float*)(ws + OFF_V);
    float* alignP = (float*)(ws + OFF_AL);
    unsigned int* ctr = (unsigned int*)(ws + OFF_CT);

    prep_kernel<<<512, 256, 0, stream>>>(feats, bfS, sq, U, V, alignP, ctr);
    band_kernel<<<NBLK, 256, 0, stream>>>(bfS, sq, U, V, alignP, ctr, out);
}

// Round 13
// 171.009 us; speedup vs baseline: 1.3052x; 1.3052x over previous
//
#include <hip/hip_runtime.h>

#define N_HALF 8192
#define D 128
#define NBLK 2080

typedef __bf16 bf16x8 __attribute__((ext_vector_type(8)));
typedef float f32x4 __attribute__((ext_vector_type(4)));

// ws layout (4327440 B):
// [0,       4194304)  bfS     -- bf16 features, MFMA-fragment-major:
//                        frag(T,kk,ni): elem ((T*4+kk)*4+ni)*512 + lane*8 + j
//                        holds row T*64+ni*16+(lane&15), k = kk*32+(lane>>4)*8+j
// [4194304, 4259840)  sq      (16384 f32)  -- exact fp32 |row|^2
// [4259840, 4292608)  U       (8192 f32)   -- rowsum_aa + rowsum_ab
// [4292608, 4325376)  V       (8192 f32)   -- colsum_ab + rowsum_bb
// [4325376, 4327424)  alignP  (512 f32)    -- per-prep-block align partials
// [4327424, 4327440)  ctr     (4 u32)      -- 0: blocks-done counter
#define OFF_SQ 4194304
#define OFF_U  4259840
#define OFF_V  4292608
#define OFF_AL 4325376
#define OFF_CT 4327424

__device__ __forceinline__ unsigned short f2bf(float f) {
    unsigned int u = __float_as_uint(f);
    u += 0x7fffu + ((u >> 16) & 1u);   // round-to-nearest-even
    return (unsigned short)(u >> 16);
}

__device__ __forceinline__ void async_cp16(const unsigned short* g, unsigned short* l) {
    __builtin_amdgcn_global_load_lds(
        (const __attribute__((address_space(1))) void*)g,
        (__attribute__((address_space(3))) void*)l, 16, 0, 0);
}

// ---- prep: block-local fragment emission (proven R9/R11 version) + ctr zero
__global__ __launch_bounds__(256) void prep_kernel(
    const float* __restrict__ feats, unsigned short* __restrict__ bfS,
    float* __restrict__ sq, float* __restrict__ U, float* __restrict__ V,
    float* __restrict__ alignP, unsigned int* __restrict__ ctr)
{
    __shared__ float ld[32 * 132];
    __shared__ float nrm[32];
    __shared__ float alg[16];

    const int b = blockIdx.x;        // 0..511
    const int t = threadIdx.x;
    const int A0 = b * 16;

#pragma unroll
    for (int it = 0; it < 4; ++it) {
        int idx = it * 256 + t;
        int row = idx >> 5;
        int c4 = idx & 31;
        int grow = (row < 16) ? (A0 + row) : (N_HALF + A0 + row - 16);
        *(float4*)&ld[row * 132 + c4 * 4] =
            *(const float4*)(feats + (size_t)grow * D + c4 * 4);
    }
    if (t < 16)       U[A0 + t] = 0.f;
    else if (t < 32)  V[A0 + t - 16] = 0.f;
    if (b == 0 && t >= 32 && t < 36) ctr[t - 32] = 0u;
    __syncthreads();

    const int wave = t >> 6, lane = t & 63;
    {   // norms
        int r = 8 * wave + (lane >> 3);
        int k0 = (lane & 7) * 16;
        float s = 0.f;
#pragma unroll
        for (int k = 0; k < 16; k += 4) {
            float4 v = *(const float4*)&ld[r * 132 + k0 + k];
            s += v.x * v.x + v.y * v.y + v.z * v.z + v.w * v.w;
        }
        s += __shfl_xor(s, 1);
        s += __shfl_xor(s, 2);
        s += __shfl_xor(s, 4);
        if ((lane & 7) == 0) {
            nrm[r] = s;
            int grow = (r < 16) ? (A0 + r) : (N_HALF + A0 + r - 16);
            sq[grow] = s;
        }
    }
    __syncthreads();
    if (wave < 2) {   // exact diag alignment term
        int r = 8 * wave + (lane >> 3);
        int k0 = (lane & 7) * 16;
        float s = 0.f;
#pragma unroll
        for (int k = 0; k < 16; k += 4) {
            float4 a = *(const float4*)&ld[r * 132 + k0 + k];
            float4 bb = *(const float4*)&ld[(r + 16) * 132 + k0 + k];
            s += a.x * bb.x + a.y * bb.y + a.z * bb.z + a.w * bb.w;
        }
        s += __shfl_xor(s, 1);
        s += __shfl_xor(s, 2);
        s += __shfl_xor(s, 4);
        if ((lane & 7) == 0) {
            float d2 = fmaxf(nrm[r] + nrm[r + 16] - 2.0f * s, 0.0f);
            alg[r] = -__logf(d2 + 1.0f);
        }
    }
    const int l = (t >> 2) & 15, j2 = t & 3, q = t >> 6;
    const int Ta = b >> 2, ni = b & 3;
#pragma unroll
    for (int kk = 0; kk < 4; ++kk) {
        float2 va = *(const float2*)&ld[l * 132 + kk * 32 + q * 8 + j2 * 2];
        float2 vb = *(const float2*)&ld[(l + 16) * 132 + kk * 32 + q * 8 + j2 * 2];
        unsigned int ua = ((unsigned int)f2bf(va.y) << 16) | f2bf(va.x);
        unsigned int ub = ((unsigned int)f2bf(vb.y) << 16) | f2bf(vb.x);
        ((unsigned int*)bfS)[((size_t)((Ta * 4 + kk) * 4 + ni)) * 256 + t] = ua;
        ((unsigned int*)bfS)[((size_t)(((128 + Ta) * 4 + kk) * 4 + ni)) * 256 + t] = ub;
    }
    __syncthreads();
    if (t == 0) {
        float s = 0.f;
#pragma unroll
        for (int r = 0; r < 16; ++r) s += alg[r];
        alignP[b] = s;
    }
}

// ---- band kernel: block = 256-row band x 4 col-tiles(64). 4 stacked waves x 64 rows.
// R12 structure with the spill fixed: __launch_bounds__(256,2) gives the 256-VGPR
// budget the af[4][4]+acc[4][4] live set (~200) needs. 2 blocks/CU (66KB LDS).
__global__ __launch_bounds__(256, 2) void band_kernel(
    const unsigned short* __restrict__ bfS, const float* __restrict__ sq,
    float* __restrict__ U, float* __restrict__ V,
    const float* __restrict__ alignP, unsigned int* __restrict__ ctr,
    unsigned int* __restrict__ out)
{
    __shared__ unsigned short lB[2][8192];   // 2 x 16 KB
    __shared__ float ps[4];
    __shared__ int lastFlag;

    int kind, band, c0;
    {
        int id = blockIdx.x;
        if (id < 1024) { kind = 0; band = id & 31; c0 = id >> 5; }
        else {
            int t = id - 1024;
            kind = 1;
            if (t >= 528) { t -= 528; kind = 2; }
            int bb_ = 0;
            while (t >= 32 - bb_) { t -= 32 - bb_; ++bb_; }   // <=31 iters, scalar
            band = bb_; c0 = bb_ + t;
        }
    }
    const int js = c0 * 4, je = js + 4;
    const bool sym = (kind != 0);

    const int wave = threadIdx.x >> 6, lane = threadIdx.x & 63;
    const int l15 = lane & 15, quad = lane >> 4;

    const int rtile = band * 4 + wave;            // wave's 64-row tile (0..127)
    const int wRow0 = rtile * 64;                 // within-half row base
    const int T_A = (kind == 2 ? 128 : 0) + rtile;
    const int T_B0 = (kind == 1 ? 0 : 128);
    const int rowSqB = (kind == 2 ? N_HALF : 0);
    const int colSqB = (kind == 1 ? 0 : N_HALF);
    float* const rowDst = (kind == 2) ? V : U;
    float* const colDst = (kind == 1) ? U : V;

    // A fragments (64 rows), scaled by -2 exactly: (x^0x8000)+0x0080 per bf16
    bf16x8 af[4][4];
#pragma unroll
    for (int mi = 0; mi < 4; ++mi)
#pragma unroll
        for (int kk = 0; kk < 4; ++kk) {
            union { uint4 u; bf16x8 v; } c;
            c.u = *(const uint4*)(bfS + ((size_t)((T_A * 4 + kk) * 4 + mi)) * 512 + lane * 8);
            c.u.x = (c.u.x ^ 0x80008000u) + 0x00800080u;
            c.u.y = (c.u.y ^ 0x80008000u) + 0x00800080u;
            c.u.z = (c.u.z ^ 0x80008000u) + 0x00800080u;
            c.u.w = (c.u.w ^ 0x80008000u) + 0x00800080u;
            af[mi][kk] = c.v;
        }

    float rs1[16];
#pragma unroll
    for (int mi = 0; mi < 4; ++mi)
#pragma unroll
        for (int r = 0; r < 4; ++r)
            rs1[mi * 4 + r] = sq[rowSqB + wRow0 + mi * 16 + quad * 4 + r] + 1.0f;

    float rowAcc[16];
#pragma unroll
    for (int x = 0; x < 16; ++x) rowAcc[x] = 0.f;

    // stage tile t (16 KB contiguous): wave copies 4KB via 4 x 1KB DMA instrs
    auto stage = [&](int t, int s) {
        const unsigned short* src = bfS + ((size_t)(T_B0 + t)) * 8192 + wave * 2048 + lane * 8;
        unsigned short* dst = &lB[s][wave * 2048];
#pragma unroll
        for (int k = 0; k < 4; ++k)
            async_cp16(src + k * 512, dst + k * 512);
    };

    stage(js, 0);
    float csqN[4];
#pragma unroll
    for (int ni = 0; ni < 4; ++ni)
        csqN[ni] = sq[colSqB + js * 64 + ni * 16 + l15];

    float savedCol[4];
    int savedJ = -1;

    for (int t = js; t < je; ++t) {
        const int s = (t - js) & 1;
        __syncthreads();                 // drains DMA(t) + prev-step atomics
        if (t + 1 < je) stage(t + 1, s ^ 1);

        if (savedJ >= 0) {               // flush previous step's col atomics
#pragma unroll
            for (int ni = 0; ni < 4; ++ni) {
                float cv = savedCol[ni];
                cv += __shfl_xor(cv, 16);
                cv += __shfl_xor(cv, 32);
                if (quad == 0) atomicAdd(&colDst[savedJ + ni * 16 + l15], cv);
            }
            savedJ = -1;
        }

        const int jn = (t + 1 < je) ? t + 1 : t;
        float csq[4] = {csqN[0], csqN[1], csqN[2], csqN[3]};
#pragma unroll
        for (int ni = 0; ni < 4; ++ni)
            csqN[ni] = sq[colSqB + jn * 64 + ni * 16 + l15];

        if (sym && t < rtile) continue;  // tile fully below this wave's diagonal

        // acc init = |a|^2 + |b|^2 + 1; MFMA adds -2*dot => acc = d2+1
        f32x4 acc[4][4];
#pragma unroll
        for (int mi = 0; mi < 4; ++mi)
#pragma unroll
            for (int ni = 0; ni < 4; ++ni)
#pragma unroll
                for (int r = 0; r < 4; ++r)
                    acc[mi][ni][r] = rs1[mi * 4 + r] + csq[ni];

#pragma unroll
        for (int kk = 0; kk < 4; ++kk) {
            bf16x8 bfr[4];
#pragma unroll
            for (int ni = 0; ni < 4; ++ni)
                bfr[ni] = *(const bf16x8*)&lB[s][(kk * 4 + ni) * 512 + lane * 8];
#pragma unroll
            for (int mi = 0; mi < 4; ++mi)
#pragma unroll
                for (int ni = 0; ni < 4; ++ni)
                    acc[mi][ni] = __builtin_amdgcn_mfma_f32_16x16x32_bf16(
                        af[mi][kk], bfr[ni], acc[mi][ni], 0, 0, 0);
        }

        const bool maskDiag = sym && (t == rtile);
        float colPart[4] = {0.f, 0.f, 0.f, 0.f};
#pragma unroll
        for (int mi = 0; mi < 4; ++mi)
#pragma unroll
            for (int ni = 0; ni < 4; ++ni)
#pragma unroll
                for (int r = 0; r < 4; ++r) {
                    float sim = __builtin_amdgcn_rcpf(fmaxf(acc[mi][ni][r], 1.0f));
                    if (maskDiag && (ni * 16 + l15) <= (mi * 16 + quad * 4 + r))
                        sim = 0.0f;      // strict upper only on diagonal tiles
                    rowAcc[mi * 4 + r] += sim;
                    colPart[ni] += sim;
                }
#pragma unroll
        for (int ni = 0; ni < 4; ++ni) savedCol[ni] = colPart[ni];
        savedJ = t * 64;
    }

    if (savedJ >= 0) {   // final col flush
#pragma unroll
        for (int ni = 0; ni < 4; ++ni) {
            float cv = savedCol[ni];
            cv += __shfl_xor(cv, 16);
            cv += __shfl_xor(cv, 32);
            if (quad == 0) atomicAdd(&colDst[savedJ + ni * 16 + l15], cv);
        }
    }
    // row flush: reduce over 16 l15 lanes, one atomic per row, once per job
#pragma unroll
    for (int x = 0; x < 16; ++x) {
        float v = rowAcc[x];
        v += __shfl_xor(v, 1);
        v += __shfl_xor(v, 2);
        v += __shfl_xor(v, 4);
        v += __shfl_xor(v, 8);
        if (l15 == 0)
            atomicAdd(&rowDst[wRow0 + (x >> 2) * 16 + quad * 4 + (x & 3)], v);
    }

    // ---- fused tail: last block reduces U/V + alignP (R10-proven mechanics)
    __syncthreads();
    if (threadIdx.x == 0) {
        __threadfence();
        unsigned int old = atomicAdd(&ctr[0], 1u);
        lastFlag = (old == (unsigned int)(NBLK - 1));
    }
    __syncthreads();
    if (lastFlag) {
        float sum = 0.f;
        for (int i = threadIdx.x; i < N_HALF; i += 256) {
            float u = __hip_atomic_load(&U[i], __ATOMIC_RELAXED, __HIP_MEMORY_SCOPE_AGENT);
            float v = __hip_atomic_load(&V[i], __ATOMIC_RELAXED, __HIP_MEMORY_SCOPE_AGENT);
            sum += __logf(u) + __logf(v);
        }
        float a = 0.f;
        for (int i = threadIdx.x; i < 512; i += 256) a += alignP[i];
        float m = a - 0.5f * sum;
#pragma unroll
        for (int off = 32; off; off >>= 1) m += __shfl_xor(m, off);
        if (lane == 0) ps[wave] = m;
        __syncthreads();
        if (threadIdx.x == 0) {
            float loss = -((ps[0] + ps[1] + ps[2] + ps[3]) / (float)N_HALF);
            unsigned int h = (unsigned int)f2bf(loss);
            out[0] = (h << 16) | h;   // fp32 reader: loss @ bf16 precision
        }
    }
}

extern "C" void kernel_launch(void* const* d_in, const int* in_sizes, int n_in,
                              void* d_out, int out_size, void* d_ws, size_t ws_size,
                              hipStream_t stream)
{
    const float* feats = (const float*)d_in[0];
    unsigned int* out = (unsigned int*)d_out;
    char* ws = (char*)d_ws;
    unsigned short* bfS = (unsigned short*)(ws);
    float* sq     = (float*)(ws + OFF_SQ);
    float* U      = (float*)(ws + OFF_U);
    float* V      = (float*)(ws + OFF_V);
    float* alignP = (float*)(ws + OFF_AL);
    unsigned int* ctr = (unsigned int*)(ws + OFF_CT);

    prep_kernel<<<512, 256, 0, stream>>>(feats, bfS, sq, U, V, alignP, ctr);
    band_kernel<<<NBLK, 256, 0, stream>>>(bfS, sq, U, V, alignP, ctr, out);
}

// Round 14
// 130.677 us; speedup vs baseline: 1.7080x; 1.3086x over previous
//
#include <hip/hip_runtime.h>

#define N_HALF 8192
#define D 128
#define NBLK 2112

typedef __bf16 bf16x8 __attribute__((ext_vector_type(8)));
typedef float f32x4 __attribute__((ext_vector_type(4)));

// ws layout (4327424 B):
// [0,       4194304)  bfS     -- bf16 features, MFMA-fragment-major:
//                        frag(T,kk,ni): elem ((T*4+kk)*4+ni)*512 + lane*8 + j
//                        holds row T*64+ni*16+(lane&15), k = kk*32+(lane>>4)*8+j
// [4194304, 4259840)  sq      (16384 f32)  -- exact fp32 |row|^2
// [4259840, 4292608)  U       (8192 f32)   -- rowsum_aa + rowsum_ab
// [4292608, 4325376)  V       (8192 f32)   -- colsum_ab + rowsum_bb
// [4325376, 4327424)  alignP  (512 f32)    -- per-a-block align partials
#define OFF_SQ 4194304
#define OFF_U  4259840
#define OFF_V  4292608
#define OFF_AL 4325376

__device__ __forceinline__ unsigned short f2bf(float f) {
    unsigned int u = __float_as_uint(f);
    u += 0x7fffu + ((u >> 16) & 1u);   // round-to-nearest-even
    return (unsigned short)(u >> 16);
}

__device__ __forceinline__ void async_cp16(const unsigned short* g, unsigned short* l) {
    __builtin_amdgcn_global_load_lds(
        (const __attribute__((address_space(1))) void*)g,
        (__attribute__((address_space(3))) void*)l, 16, 0, 0);
}

// ---- prep v2: 1024 blocks, one 16-row single-side slice each (2x parallelism
// vs R11's 512). a-blocks also compute the exact diag-align term, reading the
// paired b-rows straight from global (L2-hot; b-norms recomputed locally).
__global__ __launch_bounds__(256) void prep_kernel(
    const float* __restrict__ feats, unsigned short* __restrict__ bfS,
    float* __restrict__ sq, float* __restrict__ U, float* __restrict__ V,
    float* __restrict__ alignP)
{
    __shared__ float ld[16 * 132];
    __shared__ float alg[16];

    const int side = blockIdx.x >> 9;          // 0 = a, 1 = b
    const int idx = blockIdx.x & 511;
    const int g0 = idx * 16;                   // first row within the half
    const int R = side * N_HALF + g0;          // global feature-row base
    const int t = threadIdx.x;

    // stage 16 rows (8 KB) coalesced
#pragma unroll
    for (int it = 0; it < 2; ++it) {
        int i4 = it * 256 + t;                 // 0..511 float4 slots
        int row = i4 >> 5, c4 = i4 & 31;
        *(float4*)&ld[row * 132 + c4 * 4] =
            *(const float4*)(feats + (size_t)(R + row) * D + c4 * 4);
    }
    if (t < 16) { if (side == 0) U[g0 + t] = 0.f; else V[g0 + t] = 0.f; }
    __syncthreads();

    const int lane = t & 63;
    const int r = t >> 4;                      // row 0..15 (16 threads/row)
    const int c = t & 15;                      // thread-within-row
    // norm of own row (8 elems/thread, butterfly over the 16 row-threads)
    float sa = 0.f;
#pragma unroll
    for (int k = 0; k < 8; k += 4) {
        float4 v = *(const float4*)&ld[r * 132 + c * 8 + k];
        sa += v.x * v.x + v.y * v.y + v.z * v.z + v.w * v.w;
    }
    sa += __shfl_xor(sa, 1);
    sa += __shfl_xor(sa, 2);
    sa += __shfl_xor(sa, 4);
    sa += __shfl_xor(sa, 8);
    if (c == 0) sq[R + r] = sa;

    if (side == 0) {   // diag alignment: dot(a_r, b_r) + local b-norm
        float dt = 0.f, sb = 0.f;
        const float* brow = feats + (size_t)(N_HALF + g0 + r) * D + c * 8;
#pragma unroll
        for (int k = 0; k < 8; k += 4) {
            float4 bv = *(const float4*)(brow + k);
            float4 av = *(const float4*)&ld[r * 132 + c * 8 + k];
            dt += av.x * bv.x + av.y * bv.y + av.z * bv.z + av.w * bv.w;
            sb += bv.x * bv.x + bv.y * bv.y + bv.z * bv.z + bv.w * bv.w;
        }
        dt += __shfl_xor(dt, 1); sb += __shfl_xor(sb, 1);
        dt += __shfl_xor(dt, 2); sb += __shfl_xor(sb, 2);
        dt += __shfl_xor(dt, 4); sb += __shfl_xor(sb, 4);
        dt += __shfl_xor(dt, 8); sb += __shfl_xor(sb, 8);
        if (c == 0) {
            float d2 = fmaxf(sa + sb - 2.0f * dt, 0.0f);
            alg[r] = -__logf(d2 + 1.0f);
        }
    }

    // fragment emission: (T = side*128 + idx>>2, ni = idx&3), 4 kk -> 4 x 1KB
    const int l = (t >> 2) & 15, j2 = t & 3, q = t >> 6;
    const size_t Tni = (size_t)(((side * 128 + (idx >> 2)) * 4) * 4 + (idx & 3));
#pragma unroll
    for (int kk = 0; kk < 4; ++kk) {
        float2 va = *(const float2*)&ld[l * 132 + kk * 32 + q * 8 + j2 * 2];
        unsigned int ua = ((unsigned int)f2bf(va.y) << 16) | f2bf(va.x);
        ((unsigned int*)bfS)[(Tni + (size_t)kk * 4) * 256 + t] = ua;
    }
    if (side == 0) {
        __syncthreads();
        if (t == 0) {
            float s = 0.f;
#pragma unroll
            for (int rr = 0; rr < 16; ++rr) s += alg[rr];
            alignP[idx] = s;
        }
    }
}

// ---- band kernel: R11-proven structure (128-row band x 8 col-tiles, 4 waves
// x 32 rows, 16KB B dbuf, 4 blocks/CU) with float2-PACKED epilogue/acc-init
// (targets v_pk_add_f32 / v_pk_max_f32). Jobs: ab 1024 + aa 544 + bb 544.
__global__ __launch_bounds__(256, 4) void band_kernel(
    const unsigned short* __restrict__ bfS, const float* __restrict__ sq,
    float* __restrict__ U, float* __restrict__ V)
{
    __shared__ unsigned short lB[2][64 * D];   // 2 x 16 KB

    int kind, band, js;
    {
        int id = blockIdx.x;
        if (id < 1024) { kind = 0; band = id & 63; js = (id >> 6) * 8; }
        else {
            int t = id - 1024;
            kind = 1;
            if (t >= 544) { t -= 544; kind = 2; }
            int g = 0;
            while (t >= 4 * (16 - g)) { t -= 4 * (16 - g); ++g; }   // <=15 iters
            band = 4 * g + (t & 3);
            js = 8 * (g + (t >> 2));
        }
    }
    const int je = js + 8;
    const bool sym = (kind != 0);

    const int wave = threadIdx.x >> 6, lane = threadIdx.x & 63;
    const int l15 = lane & 15, quad = lane >> 4;

    const int T_Aw = (kind == 2 ? 128 : 0) + 2 * band + (wave >> 1);
    const int niA0 = (wave & 1) * 2;
    const int T_B0 = (kind == 1 ? 0 : 128);
    const int rowSqB = (kind == 2 ? N_HALF : 0);
    const int colSqB = (kind == 1 ? 0 : N_HALF);
    float* const rowDst = (kind == 2) ? V : U;
    float* const colDst = (kind == 1) ? U : V;
    const int wRow0 = band * 128 + wave * 32;

    // A fragments (32 rows), scaled by -2 exactly: (x^0x8000)+0x0080 per bf16
    bf16x8 af[2][4];
#pragma unroll
    for (int mi = 0; mi < 2; ++mi)
#pragma unroll
        for (int kk = 0; kk < 4; ++kk) {
            union { uint4 u; bf16x8 v; } c;
            c.u = *(const uint4*)(bfS + ((size_t)((T_Aw * 4 + kk) * 4 + niA0 + mi)) * 512 + lane * 8);
            c.u.x = (c.u.x ^ 0x80008000u) + 0x00800080u;
            c.u.y = (c.u.y ^ 0x80008000u) + 0x00800080u;
            c.u.z = (c.u.z ^ 0x80008000u) + 0x00800080u;
            c.u.w = (c.u.w ^ 0x80008000u) + 0x00800080u;
            af[mi][kk] = c.v;
        }

    // rs2[mi*2+rh] = {|a|^2+1 of rows quad*4+2rh, +2rh+1}  (packed pairs)
    float2 rs2[4];
#pragma unroll
    for (int mi = 0; mi < 2; ++mi)
#pragma unroll
        for (int rh = 0; rh < 2; ++rh) {
            const float* p = sq + rowSqB + wRow0 + mi * 16 + quad * 4 + 2 * rh;
            rs2[mi * 2 + rh] = make_float2(p[0] + 1.0f, p[1] + 1.0f);
        }

    float2 rowAcc2[4];
#pragma unroll
    for (int x = 0; x < 4; ++x) rowAcc2[x] = make_float2(0.f, 0.f);

    auto stage = [&](int t, int s) {
        const unsigned short* src = bfS + ((size_t)(T_B0 + t)) * 8192 + wave * 2048 + lane * 8;
        unsigned short* dst = &lB[s][wave * 2048];
#pragma unroll
        for (int k = 0; k < 4; ++k)
            async_cp16(src + k * 512, dst + k * 512);
    };

    stage(js, 0);
    float csqN[4];
#pragma unroll
    for (int ni = 0; ni < 4; ++ni)
        csqN[ni] = sq[colSqB + js * 64 + ni * 16 + l15];

    float savedCol[4];
    int savedJ = -1;

    for (int t = js; t < je; ++t) {
        const int s = (t - js) & 1;
        __syncthreads();                 // drains DMA(t) + prev-step atomics
        if (t + 1 < je) stage(t + 1, s ^ 1);

        if (savedJ >= 0) {               // flush previous step's col atomics
#pragma unroll
            for (int ni = 0; ni < 4; ++ni) {
                float cv = savedCol[ni];
                cv += __shfl_xor(cv, 16);
                cv += __shfl_xor(cv, 32);
                if (quad == 0) atomicAdd(&colDst[savedJ + ni * 16 + l15], cv);
            }
            savedJ = -1;
        }

        const int jn = (t + 1 < je) ? t + 1 : t;
        float csq[4] = {csqN[0], csqN[1], csqN[2], csqN[3]};
#pragma unroll
        for (int ni = 0; ni < 4; ++ni)
            csqN[ni] = sq[colSqB + jn * 64 + ni * 16 + l15];

        if (sym && (t * 64 + 64) <= wRow0) continue;   // fully below diagonal

        // acc init = |a|^2 + |b|^2 + 1 (packed); MFMA adds -2*dot => acc = d2+1
        f32x4 acc[2][4];
#pragma unroll
        for (int mi = 0; mi < 2; ++mi)
#pragma unroll
            for (int ni = 0; ni < 4; ++ni) {
                float2 c2 = make_float2(csq[ni], csq[ni]);
                float2 lo = make_float2(rs2[mi * 2].x + c2.x, rs2[mi * 2].y + c2.y);
                float2 hi = make_float2(rs2[mi * 2 + 1].x + c2.x, rs2[mi * 2 + 1].y + c2.y);
                acc[mi][ni][0] = lo.x; acc[mi][ni][1] = lo.y;
                acc[mi][ni][2] = hi.x; acc[mi][ni][3] = hi.y;
            }

#pragma unroll
        for (int kk = 0; kk < 4; ++kk) {
            bf16x8 bfr[4];
#pragma unroll
            for (int ni = 0; ni < 4; ++ni)
                bfr[ni] = *(const bf16x8*)&lB[s][(kk * 4 + ni) * 512 + lane * 8];
#pragma unroll
            for (int mi = 0; mi < 2; ++mi)
#pragma unroll
                for (int ni = 0; ni < 4; ++ni)
                    acc[mi][ni] = __builtin_amdgcn_mfma_f32_16x16x32_bf16(
                        af[mi][kk], bfr[ni], acc[mi][ni], 0, 0, 0);
        }

        const bool maskDiag = sym && (t * 64 < wRow0 + 32);
        if (!maskDiag) {
            // packed epilogue: pk_max, rcp, pk_add accumulation
            float2 cp[4];
#pragma unroll
            for (int ni = 0; ni < 4; ++ni) cp[ni] = make_float2(0.f, 0.f);
#pragma unroll
            for (int mi = 0; mi < 2; ++mi)
#pragma unroll
                for (int ni = 0; ni < 4; ++ni) {
                    float2 lo = make_float2(fmaxf(acc[mi][ni][0], 1.0f),
                                            fmaxf(acc[mi][ni][1], 1.0f));
                    float2 hi = make_float2(fmaxf(acc[mi][ni][2], 1.0f),
                                            fmaxf(acc[mi][ni][3], 1.0f));
                    float2 slo = make_float2(__builtin_amdgcn_rcpf(lo.x),
                                             __builtin_amdgcn_rcpf(lo.y));
                    float2 shi = make_float2(__builtin_amdgcn_rcpf(hi.x),
                                             __builtin_amdgcn_rcpf(hi.y));
                    rowAcc2[mi * 2].x += slo.x;     rowAcc2[mi * 2].y += slo.y;
                    rowAcc2[mi * 2 + 1].x += shi.x; rowAcc2[mi * 2 + 1].y += shi.y;
                    cp[ni].x += slo.x + shi.x;
                    cp[ni].y += slo.y + shi.y;
                }
#pragma unroll
            for (int ni = 0; ni < 4; ++ni) savedCol[ni] = cp[ni].x + cp[ni].y;
        } else {
            // scalar masked path (rare: diagonal-overlap tiles only)
            float colPart[4] = {0.f, 0.f, 0.f, 0.f};
#pragma unroll
            for (int mi = 0; mi < 2; ++mi)
#pragma unroll
                for (int ni = 0; ni < 4; ++ni)
#pragma unroll
                    for (int r = 0; r < 4; ++r) {
                        float sim = __builtin_amdgcn_rcpf(fmaxf(acc[mi][ni][r], 1.0f));
                        if ((t * 64 + ni * 16 + l15) <= (wRow0 + mi * 16 + quad * 4 + r))
                            sim = 0.0f;   // strict upper only
                        if (r & 1) rowAcc2[mi * 2 + (r >> 1)].y += sim;
                        else       rowAcc2[mi * 2 + (r >> 1)].x += sim;
                        colPart[ni] += sim;
                    }
#pragma unroll
            for (int ni = 0; ni < 4; ++ni) savedCol[ni] = colPart[ni];
        }
        savedJ = t * 64;
    }

    if (savedJ >= 0) {   // final col flush
#pragma unroll
        for (int ni = 0; ni < 4; ++ni) {
            float cv = savedCol[ni];
            cv += __shfl_xor(cv, 16);
            cv += __shfl_xor(cv, 32);
            if (quad == 0) atomicAdd(&colDst[savedJ + ni * 16 + l15], cv);
        }
    }
    // row flush: reduce over 16 l15 lanes, one atomic per row, once per job
#pragma unroll
    for (int x = 0; x < 8; ++x) {
        float v = (x & 1) ? rowAcc2[x >> 1].y : rowAcc2[x >> 1].x;
        v += __shfl_xor(v, 1);
        v += __shfl_xor(v, 2);
        v += __shfl_xor(v, 4);
        v += __shfl_xor(v, 8);
        if (l15 == 0)
            atomicAdd(&rowDst[wRow0 + (x >> 2) * 16 + quad * 4 + (x & 3)], v);
    }
}

// ---- tail: sum logs of U,V + align partials -> loss (single block)
__global__ __launch_bounds__(1024) void tail_kernel(
    const float* __restrict__ U, const float* __restrict__ V,
    const float* __restrict__ alignP, unsigned int* __restrict__ out)
{
    const int tid = threadIdx.x;
    float s = 0.f;
    const float4* U4 = (const float4*)U;
    const float4* V4 = (const float4*)V;
#pragma unroll
    for (int k = 0; k < 2; ++k) {
        float4 u = U4[tid * 2 + k];
        float4 v = V4[tid * 2 + k];
        s += __logf(u.x) + __logf(u.y) + __logf(u.z) + __logf(u.w);
        s += __logf(v.x) + __logf(v.y) + __logf(v.z) + __logf(v.w);
    }
    float a = 0.f;
    if (tid < 128) {
        float4 t4 = ((const float4*)alignP)[tid];
        a = t4.x + t4.y + t4.z + t4.w;
    }
    float m = a - 0.5f * s;
#pragma unroll
    for (int off = 32; off; off >>= 1) m += __shfl_xor(m, off);
    __shared__ float ps[16];
    if ((tid & 63) == 0) ps[tid >> 6] = m;
    __syncthreads();
    if (tid == 0) {
        float tot = 0.f;
#pragma unroll
        for (int w = 0; w < 16; ++w) tot += ps[w];
        float loss = -(tot / (float)N_HALF);
        unsigned int h = (unsigned int)f2bf(loss);
        out[0] = (h << 16) | h;   // fp32 reader: loss @ bf16 precision; bf16 reader: h
    }
}

extern "C" void kernel_launch(void* const* d_in, const int* in_sizes, int n_in,
                              void* d_out, int out_size, void* d_ws, size_t ws_size,
                              hipStream_t stream)
{
    const float* feats = (const float*)d_in[0];
    unsigned int* out = (unsigned int*)d_out;
    char* ws = (char*)d_ws;
    unsigned short* bfS = (unsigned short*)(ws);
    float* sq     = (float*)(ws + OFF_SQ);
    float* U      = (float*)(ws + OFF_U);
    float* V      = (float*)(ws + OFF_V);
    float* alignP = (float*)(ws + OFF_AL);

    prep_kernel<<<1024, 256, 0, stream>>>(feats, bfS, sq, U, V, alignP);
    band_kernel<<<NBLK, 256, 0, stream>>>(bfS, sq, U, V);
    tail_kernel<<<1, 1024, 0, stream>>>(U, V, alignP, out);
}

// Round 15
// 124.107 us; speedup vs baseline: 1.7984x; 1.0529x over previous
//
#include <hip/hip_runtime.h>

#define N_HALF 8192
#define D 128
#define NBLK 2112

typedef float f32x4 __attribute__((ext_vector_type(4)));

// ws layout (4327424 B):
// [0,       2097152)  bfA  -- fp8 e4m3 of (-2*x), fragment-major kk-paired:
//                       frag(T,p,ni) @ ((T*2+p)*4+ni)*1024; lane l byte [l*16+h*8+j]
//                       = row T*64+ni*16+(l&15), k = (2p+h)*32+(l>>4)*8+j
// [2097152, 4194304)  bfB  -- fp8 e4m3 of (x), same layout
// [4194304, 4259840)  sq      (16384 f32)  -- exact fp32 |row|^2
// [4259840, 4292608)  U       (8192 f32)   -- rowsum_aa + rowsum_ab
// [4292608, 4325376)  V       (8192 f32)   -- colsum_ab + rowsum_bb
// [4325376, 4327424)  alignP  (512 f32)    -- per-a-block align partials
#define OFF_B  2097152
#define OFF_SQ 4194304
#define OFF_U  4259840
#define OFF_V  4292608
#define OFF_AL 4325376

union Frag { uint4 u; long h[2]; };

__device__ __forceinline__ unsigned short f2bf(float f) {
    unsigned int u = __float_as_uint(f);
    u += 0x7fffu + ((u >> 16) & 1u);   // round-to-nearest-even
    return (unsigned short)(u >> 16);
}

__device__ __forceinline__ void async_cp16(const void* g, void* l) {
    __builtin_amdgcn_global_load_lds(
        (const __attribute__((address_space(1))) void*)g,
        (__attribute__((address_space(3))) void*)l, 16, 0, 0);
}

// ---- prep: 1024 blocks, one 16-row single-side slice each. Exact fp32 norms +
// diag-align; emits fp8 fragments: bfA = fp8(-2x), bfB = fp8(x) (kk-paired).
__global__ __launch_bounds__(256) void prep_kernel(
    const float* __restrict__ feats, unsigned char* __restrict__ bfA,
    unsigned char* __restrict__ bfB,
    float* __restrict__ sq, float* __restrict__ U, float* __restrict__ V,
    float* __restrict__ alignP)
{
    __shared__ float ld[16 * 132];
    __shared__ float alg[16];

    const int side = blockIdx.x >> 9;          // 0 = a, 1 = b
    const int idx = blockIdx.x & 511;
    const int g0 = idx * 16;                   // first row within the half
    const int R = side * N_HALF + g0;          // global feature-row base
    const int t = threadIdx.x;

    // stage 16 rows (8 KB) coalesced
#pragma unroll
    for (int it = 0; it < 2; ++it) {
        int i4 = it * 256 + t;                 // 0..511 float4 slots
        int row = i4 >> 5, c4 = i4 & 31;
        *(float4*)&ld[row * 132 + c4 * 4] =
            *(const float4*)(feats + (size_t)(R + row) * D + c4 * 4);
    }
    if (t < 16) { if (side == 0) U[g0 + t] = 0.f; else V[g0 + t] = 0.f; }
    __syncthreads();

    const int r = t >> 4;                      // row 0..15 (16 threads/row)
    const int c = t & 15;
    float sa = 0.f;
#pragma unroll
    for (int k = 0; k < 8; k += 4) {
        float4 v = *(const float4*)&ld[r * 132 + c * 8 + k];
        sa += v.x * v.x + v.y * v.y + v.z * v.z + v.w * v.w;
    }
    sa += __shfl_xor(sa, 1);
    sa += __shfl_xor(sa, 2);
    sa += __shfl_xor(sa, 4);
    sa += __shfl_xor(sa, 8);
    if (c == 0) sq[R + r] = sa;

    if (side == 0) {   // exact diag alignment: dot(a_r, b_r) + local b-norm
        float dt = 0.f, sb = 0.f;
        const float* brow = feats + (size_t)(N_HALF + g0 + r) * D + c * 8;
#pragma unroll
        for (int k = 0; k < 8; k += 4) {
            float4 bv = *(const float4*)(brow + k);
            float4 av = *(const float4*)&ld[r * 132 + c * 8 + k];
            dt += av.x * bv.x + av.y * bv.y + av.z * bv.z + av.w * bv.w;
            sb += bv.x * bv.x + bv.y * bv.y + bv.z * bv.z + bv.w * bv.w;
        }
        dt += __shfl_xor(dt, 1); sb += __shfl_xor(sb, 1);
        dt += __shfl_xor(dt, 2); sb += __shfl_xor(sb, 2);
        dt += __shfl_xor(dt, 4); sb += __shfl_xor(sb, 4);
        dt += __shfl_xor(dt, 8); sb += __shfl_xor(sb, 8);
        if (c == 0) {
            float d2 = fmaxf(sa + sb - 2.0f * dt, 0.0f);
            alg[r] = -__logf(d2 + 1.0f);
        }
    }

    // fp8 fragment emission: (T = side*128+idx>>2, ni = idx&3); uint t of each
    // 1KB frag: l = t>>2, half = (t>>1)&1, j0 = (t&1)*4.
    const int l = t >> 2, half = (t >> 1) & 1, j0 = (t & 1) * 4;
    const int rloc = l & 15, quad = l >> 4;
    const size_t Tb = ((size_t)(side * 128 + (idx >> 2))) * 8 + (idx & 3);
#pragma unroll
    for (int p = 0; p < 2; ++p) {
        const int k = p * 64 + half * 32 + quad * 8 + j0;
        float4 v = *(const float4*)&ld[rloc * 132 + k];
        int ub = __builtin_amdgcn_cvt_pk_fp8_f32(v.x, v.y, 0, false);
        ub = __builtin_amdgcn_cvt_pk_fp8_f32(v.z, v.w, ub, true);
        int ua = __builtin_amdgcn_cvt_pk_fp8_f32(-2.f * v.x, -2.f * v.y, 0, false);
        ua = __builtin_amdgcn_cvt_pk_fp8_f32(-2.f * v.z, -2.f * v.w, ua, true);
        ((unsigned int*)bfA)[(Tb + p * 4) * 256 + t] = (unsigned int)ua;
        ((unsigned int*)bfB)[(Tb + p * 4) * 256 + t] = (unsigned int)ub;
    }
    if (side == 0) {
        __syncthreads();
        if (t == 0) {
            float s = 0.f;
#pragma unroll
            for (int rr = 0; rr < 16; ++rr) s += alg[rr];
            alignP[idx] = s;
        }
    }
}

// ---- band kernel: R11/R14-proven structure (128-row band x 8 col-tiles, 4 waves
// x 32 rows, B dbuf, 4 blocks/CU, packed epilogue) ported to fp8:
// A = bfA (pre-scaled -2, no VALU fixup), B tile = 8KB DMA, 8 ds_read_b128/step.
__global__ __launch_bounds__(256, 4) void band_kernel(
    const unsigned char* __restrict__ bfA, const unsigned char* __restrict__ bfB,
    const float* __restrict__ sq, float* __restrict__ U, float* __restrict__ V)
{
    __shared__ unsigned char lB[2][8192];   // 2 x 8 KB

    int kind, band, js;
    {
        int id = blockIdx.x;
        if (id < 1024) { kind = 0; band = id & 63; js = (id >> 6) * 8; }
        else {
            int t = id - 1024;
            kind = 1;
            if (t >= 544) { t -= 544; kind = 2; }
            int g = 0;
            while (t >= 4 * (16 - g)) { t -= 4 * (16 - g); ++g; }   // <=15 iters
            band = 4 * g + (t & 3);
            js = 8 * (g + (t >> 2));
        }
    }
    const int je = js + 8;
    const bool sym = (kind != 0);

    const int wave = threadIdx.x >> 6, lane = threadIdx.x & 63;
    const int l15 = lane & 15, quad = lane >> 4;

    const int T_Aw = (kind == 2 ? 128 : 0) + 2 * band + (wave >> 1);
    const int niA0 = (wave & 1) * 2;
    const int T_B0 = (kind == 1 ? 0 : 128);
    const int rowSqB = (kind == 2 ? N_HALF : 0);
    const int colSqB = (kind == 1 ? 0 : N_HALF);
    float* const rowDst = (kind == 2) ? V : U;
    float* const colDst = (kind == 1) ? U : V;
    const int wRow0 = band * 128 + wave * 32;

    // A fragments (32 rows, pre-scaled -2 in fp8): af[mi][p], 2 kk per b128
    Frag af[2][2];
#pragma unroll
    for (int mi = 0; mi < 2; ++mi)
#pragma unroll
        for (int p = 0; p < 2; ++p)
            af[mi][p].u = *(const uint4*)(bfA +
                ((size_t)T_Aw * 8 + p * 4 + niA0 + mi) * 1024 + lane * 16);

    float2 rs2[4];
#pragma unroll
    for (int mi = 0; mi < 2; ++mi)
#pragma unroll
        for (int rh = 0; rh < 2; ++rh) {
            const float* p = sq + rowSqB + wRow0 + mi * 16 + quad * 4 + 2 * rh;
            rs2[mi * 2 + rh] = make_float2(p[0] + 1.0f, p[1] + 1.0f);
        }

    float2 rowAcc2[4];
#pragma unroll
    for (int x = 0; x < 4; ++x) rowAcc2[x] = make_float2(0.f, 0.f);

    // stage tile t (8 KB contiguous): wave copies 2KB via 2 x 1KB DMA instrs
    auto stage = [&](int t, int s) {
        const unsigned char* src = bfB + (size_t)(T_B0 + t) * 8192 + wave * 2048 + lane * 16;
        unsigned char* dst = &lB[s][wave * 2048];
        async_cp16(src, dst);
        async_cp16(src + 1024, dst + 1024);
    };

    stage(js, 0);
    float csqN[4];
#pragma unroll
    for (int ni = 0; ni < 4; ++ni)
        csqN[ni] = sq[colSqB + js * 64 + ni * 16 + l15];

    float savedCol[4];
    int savedJ = -1;

    for (int t = js; t < je; ++t) {
        const int s = (t - js) & 1;
        __syncthreads();                 // drains DMA(t) + prev-step atomics
        if (t + 1 < je) stage(t + 1, s ^ 1);

        if (savedJ >= 0) {               // flush previous step's col atomics
#pragma unroll
            for (int ni = 0; ni < 4; ++ni) {
                float cv = savedCol[ni];
                cv += __shfl_xor(cv, 16);
                cv += __shfl_xor(cv, 32);
                if (quad == 0) atomicAdd(&colDst[savedJ + ni * 16 + l15], cv);
            }
            savedJ = -1;
        }

        const int jn = (t + 1 < je) ? t + 1 : t;
        float csq[4] = {csqN[0], csqN[1], csqN[2], csqN[3]};
#pragma unroll
        for (int ni = 0; ni < 4; ++ni)
            csqN[ni] = sq[colSqB + jn * 64 + ni * 16 + l15];

        if (sym && (t * 64 + 64) <= wRow0) continue;   // fully below diagonal

        // acc init = |a|^2 + |b|^2 + 1 (packed); MFMA adds -2*dot => acc = d2+1
        f32x4 acc[2][4];
#pragma unroll
        for (int mi = 0; mi < 2; ++mi)
#pragma unroll
            for (int ni = 0; ni < 4; ++ni) {
                acc[mi][ni][0] = rs2[mi * 2].x + csq[ni];
                acc[mi][ni][1] = rs2[mi * 2].y + csq[ni];
                acc[mi][ni][2] = rs2[mi * 2 + 1].x + csq[ni];
                acc[mi][ni][3] = rs2[mi * 2 + 1].y + csq[ni];
            }

#pragma unroll
        for (int p = 0; p < 2; ++p) {
            Frag bfr[4];
#pragma unroll
            for (int ni = 0; ni < 4; ++ni)
                bfr[ni].u = *(const uint4*)&lB[s][(p * 4 + ni) * 1024 + lane * 16];
#pragma unroll
            for (int h = 0; h < 2; ++h)
#pragma unroll
                for (int mi = 0; mi < 2; ++mi)
#pragma unroll
                    for (int ni = 0; ni < 4; ++ni)
                        acc[mi][ni] = __builtin_amdgcn_mfma_f32_16x16x32_fp8_fp8(
                            af[mi][p].h[h], bfr[ni].h[h], acc[mi][ni], 0, 0, 0);
        }

        const bool maskDiag = sym && (t * 64 < wRow0 + 32);
        if (!maskDiag) {
            // packed epilogue: pk_max, rcp, pk_add accumulation
            float2 cp[4];
#pragma unroll
            for (int ni = 0; ni < 4; ++ni) cp[ni] = make_float2(0.f, 0.f);
#pragma unroll
            for (int mi = 0; mi < 2; ++mi)
#pragma unroll
                for (int ni = 0; ni < 4; ++ni) {
                    float2 lo = make_float2(fmaxf(acc[mi][ni][0], 1.0f),
                                            fmaxf(acc[mi][ni][1], 1.0f));
                    float2 hi = make_float2(fmaxf(acc[mi][ni][2], 1.0f),
                                            fmaxf(acc[mi][ni][3], 1.0f));
                    float2 slo = make_float2(__builtin_amdgcn_rcpf(lo.x),
                                             __builtin_amdgcn_rcpf(lo.y));
                    float2 shi = make_float2(__builtin_amdgcn_rcpf(hi.x),
                                             __builtin_amdgcn_rcpf(hi.y));
                    rowAcc2[mi * 2].x += slo.x;     rowAcc2[mi * 2].y += slo.y;
                    rowAcc2[mi * 2 + 1].x += shi.x; rowAcc2[mi * 2 + 1].y += shi.y;
                    cp[ni].x += slo.x + shi.x;
                    cp[ni].y += slo.y + shi.y;
                }
#pragma unroll
            for (int ni = 0; ni < 4; ++ni) savedCol[ni] = cp[ni].x + cp[ni].y;
        } else {
            // scalar masked path (diagonal-overlap tiles only)
            float colPart[4] = {0.f, 0.f, 0.f, 0.f};
#pragma unroll
            for (int mi = 0; mi < 2; ++mi)
#pragma unroll
                for (int ni = 0; ni < 4; ++ni)
#pragma unroll
                    for (int r = 0; r < 4; ++r) {
                        float sim = __builtin_amdgcn_rcpf(fmaxf(acc[mi][ni][r], 1.0f));
                        if ((t * 64 + ni * 16 + l15) <= (wRow0 + mi * 16 + quad * 4 + r))
                            sim = 0.0f;   // strict upper only
                        if (r & 1) rowAcc2[mi * 2 + (r >> 1)].y += sim;
                        else       rowAcc2[mi * 2 + (r >> 1)].x += sim;
                        colPart[ni] += sim;
                    }
#pragma unroll
            for (int ni = 0; ni < 4; ++ni) savedCol[ni] = colPart[ni];
        }
        savedJ = t * 64;
    }

    if (savedJ >= 0) {   // final col flush
#pragma unroll
        for (int ni = 0; ni < 4; ++ni) {
            float cv = savedCol[ni];
            cv += __shfl_xor(cv, 16);
            cv += __shfl_xor(cv, 32);
            if (quad == 0) atomicAdd(&colDst[savedJ + ni * 16 + l15], cv);
        }
    }
    // row flush: reduce over 16 l15 lanes, one atomic per row, once per job
#pragma unroll
    for (int x = 0; x < 8; ++x) {
        float v = (x & 1) ? rowAcc2[x >> 1].y : rowAcc2[x >> 1].x;
        v += __shfl_xor(v, 1);
        v += __shfl_xor(v, 2);
        v += __shfl_xor(v, 4);
        v += __shfl_xor(v, 8);
        if (l15 == 0)
            atomicAdd(&rowDst[wRow0 + (x >> 2) * 16 + quad * 4 + (x & 3)], v);
    }
}

// ---- tail: sum logs of U,V + align partials -> loss (single block)
__global__ __launch_bounds__(1024) void tail_kernel(
    const float* __restrict__ U, const float* __restrict__ V,
    const float* __restrict__ alignP, unsigned int* __restrict__ out)
{
    const int tid = threadIdx.x;
    float s = 0.f;
    const float4* U4 = (const float4*)U;
    const float4* V4 = (const float4*)V;
#pragma unroll
    for (int k = 0; k < 2; ++k) {
        float4 u = U4[tid * 2 + k];
        float4 v = V4[tid * 2 + k];
        s += __logf(u.x) + __logf(u.y) + __logf(u.z) + __logf(u.w);
        s += __logf(v.x) + __logf(v.y) + __logf(v.z) + __logf(v.w);
    }
    float a = 0.f;
    if (tid < 128) {
        float4 t4 = ((const float4*)alignP)[tid];
        a = t4.x + t4.y + t4.z + t4.w;
    }
    float m = a - 0.5f * s;
#pragma unroll
    for (int off = 32; off; off >>= 1) m += __shfl_xor(m, off);
    __shared__ float ps[16];
    if ((tid & 63) == 0) ps[tid >> 6] = m;
    __syncthreads();
    if (tid == 0) {
        float tot = 0.f;
#pragma unroll
        for (int w = 0; w < 16; ++w) tot += ps[w];
        float loss = -(tot / (float)N_HALF);
        unsigned int h = (unsigned int)f2bf(loss);
        out[0] = (h << 16) | h;   // fp32 reader: loss @ bf16 precision; bf16 reader: h
    }
}

extern "C" void kernel_launch(void* const* d_in, const int* in_sizes, int n_in,
                              void* d_out, int out_size, void* d_ws, size_t ws_size,
                              hipStream_t stream)
{
    const float* feats = (const float*)d_in[0];
    unsigned int* out = (unsigned int*)d_out;
    char* ws = (char*)d_ws;
    unsigned char* bfA = (unsigned char*)(ws);
    unsigned char* bfB = (unsigned char*)(ws + OFF_B);
    float* sq     = (float*)(ws + OFF_SQ);
    float* U      = (float*)(ws + OFF_U);
    float* V      = (float*)(ws + OFF_V);
    float* alignP = (float*)(ws + OFF_AL);

    prep_kernel<<<1024, 256, 0, stream>>>(feats, bfA, bfB, sq, U, V, alignP);
    band_kernel<<<NBLK, 256, 0, stream>>>(bfA, bfB, sq, U, V);
    tail_kernel<<<1, 1024, 0, stream>>>(U, V, alignP, out);
}